// Round 8
// baseline (142.537 us; speedup 1.0000x reference)
//
#include <hip/hip_runtime.h>
#include <hip/hip_bf16.h>
#include <stdint.h>

using bf16x8 = __attribute__((ext_vector_type(8))) __bf16;
using f32x4  = __attribute__((ext_vector_type(4))) float;
using i32x4  = __attribute__((ext_vector_type(4))) int;

#define GBM 128
#define GBN 128
#define GBK 32
#define GTHR 256   // 4 waves, 2x2; wave tile 64x64, acc 4x4
#define NGMAX 32

__device__ __forceinline__ void gload_lds16(const void* g, void* l) {
  __builtin_amdgcn_global_load_lds((const __attribute__((address_space(1))) void*)g,
                                   (__attribute__((address_space(3))) void*)l,
                                   16, 0, 0);
}

// Pack A: x fp32 -> bf16, tile-contiguous [by][t][unit], unit(row,slot)
// holds x[row][ (slot^(row&3))*8 .. +8 ] of tile t (pre-swizzled for LDS).
__global__ __launch_bounds__(256)
void xcvt_p(const float* __restrict__ x, __bf16* __restrict__ wsA, int K, int nT) {
  const int U  = blockIdx.x * 256 + threadIdx.x;
  const int uu = U & 511;
  const int tt = (U >> 9) % nT;
  const int by = (U >> 9) / nT;
  const int row = uu >> 2, slot = uu & 3;
  const int c = slot ^ (row & 3);
  const f32x4* src = reinterpret_cast<const f32x4*>(
      x + (size_t)(by * GBM + row) * K + tt * GBK + c * 8);
  f32x4 a = src[0], b = src[1];
  bf16x8 w;
  w[0] = (__bf16)a[0]; w[1] = (__bf16)a[1]; w[2] = (__bf16)a[2]; w[3] = (__bf16)a[3];
  w[4] = (__bf16)b[0]; w[5] = (__bf16)b[1]; w[6] = (__bf16)b[2]; w[7] = (__bf16)b[3];
  *reinterpret_cast<bf16x8*>(wsA + (size_t)U * 8) = w;
}

// Fused: B (raw int32) staged via global_load_lds, dequant at fragment build.
__global__ __launch_bounds__(GTHR, 2)
void gptq_fused(const __bf16* __restrict__ wsA, const int* __restrict__ qw,
                const float* __restrict__ scales, const float* __restrict__ bias,
                float* __restrict__ out, int N, int K, int NG, int gy) {
  __shared__ __bf16 As[2][GBM * GBK];          // 2 x 8 KiB
  __shared__ int    Bs[2][GBN * GBK];          // 2 x 16 KiB (raw int32)
  __shared__ float  sS[GBN * (NGMAX + 1)];     // 16.9 KiB, stride 33 (pad)

  const int tid  = threadIdx.x;
  const int lane = tid & 63;
  const int wv   = tid >> 6;
  const int wr   = wv >> 1;   // 0..1
  const int wc   = wv & 1;    // 0..1

  // XCD-chunked mapping (grid 344 = 8*43), by-innermost => co-panel same XCD
  int wgid = blockIdx.x;
  if ((gridDim.x & 7) == 0) {
    const int q = gridDim.x >> 3;
    wgid = (blockIdx.x & 7) * q + (blockIdx.x >> 3);
  }
  const int bx = wgid / gy;
  const int by = wgid % gy;
  const int tileM = by * GBM;
  const int tileN = bx * GBN;

  const int l15 = lane & 15;
  const int l4  = lane >> 4;
  const int nT  = K / GBK;                     // 128

  // ---- preload scale panel: scales[tileN .. +128][0..NG) -> padded LDS ----
  for (int idx = tid; idx < GBN * NGMAX; idx += GTHR) {
    const int col = idx >> 5;                  // NG == 32 guaranteed by guard
    const int g   = idx & 31;
    sS[col * (NGMAX + 1) + g] = scales[(size_t)(tileN + col) * NG + g];
  }
  __syncthreads();                             // full drain: clean vmcnt queue

  f32x4 acc[4][4];
#pragma unroll
  for (int m = 0; m < 4; ++m)
#pragma unroll
    for (int n = 0; n < 4; ++n) acc[m][n] = (f32x4)0.0f;

  const __bf16* srcA = wsA + (size_t)by * nT * (GBM * GBK);

  // STAGE: 6 gload_lds16 per thread (A 2 + B 4); LDS linear, source pre-swizzled
  auto STAGE = [&](int buf, int t) {
    const __bf16* a = srcA + (size_t)t * (GBM * GBK);
#pragma unroll
    for (int i = 0; i < 2; ++i) {
      const int ub = i * 256 + wv * 64;        // uniform base unit (A: 512 units)
      gload_lds16(a + (size_t)(ub + lane) * 8, &As[buf][ub * 8]);
    }
    const int k0 = t * GBK;
#pragma unroll
    for (int i = 0; i < 4; ++i) {
      const int u = i * 256 + wv * 64 + lane;  // B: 1024 units, 8 per row
      const int row = u >> 3, sl = u & 7;
      const int j = sl ^ (row & 7);            // source int4-group
      gload_lds16(qw + (size_t)(tileN + row) * K + k0 + j * 4,
                  &Bs[buf][(i * 256 + wv * 64) * 4]);
    }
  };

  // circular, group-aligned dephase by panel
  const int t0 = ((bx * 7) % NG) * 4;          // nT = 4*NG
  auto T = [&](int i) { int t = t0 + i; return (t < nT) ? t : t - nT; };

  STAGE(0, T(0));
  STAGE(1, T(1));

  for (int i = 0; i < nT; ++i) {
    if (i + 1 < nT) { asm volatile("s_waitcnt vmcnt(6)" ::: "memory"); }
    else            { asm volatile("s_waitcnt vmcnt(0)" ::: "memory"); }
    __builtin_amdgcn_s_barrier();
    __builtin_amdgcn_sched_barrier(0);

    const int cur = i & 1;
    const int t   = T(i);
    const int g   = t >> 2;                    // GS = 4*GBK

    bf16x8 af[4];
#pragma unroll
    for (int m = 0; m < 4; ++m) {
      const int row = wr * 64 + m * 16 + l15;
      const int sl  = l4 ^ (row & 3);
      af[m] = *reinterpret_cast<const bf16x8*>(&As[cur][row * GBK + sl * 8]);
    }
#pragma unroll
    for (int n = 0; n < 4; ++n) {
      const int col = wc * 64 + n * 16 + l15;
      const int rb  = col & 7;
      const int* brow = &Bs[cur][col * GBK];
      i32x4 q0 = *reinterpret_cast<const i32x4*>(&brow[((2 * l4) ^ rb) * 4]);
      i32x4 q1 = *reinterpret_cast<const i32x4*>(&brow[((2 * l4 + 1) ^ rb) * 4]);
      const float s = sS[col * (NGMAX + 1) + g];
      bf16x8 bb;
      bb[0] = (__bf16)((float)q0[0] * s); bb[1] = (__bf16)((float)q0[1] * s);
      bb[2] = (__bf16)((float)q0[2] * s); bb[3] = (__bf16)((float)q0[3] * s);
      bb[4] = (__bf16)((float)q1[0] * s); bb[5] = (__bf16)((float)q1[1] * s);
      bb[6] = (__bf16)((float)q1[2] * s); bb[7] = (__bf16)((float)q1[3] * s);
#pragma unroll
      for (int m = 0; m < 4; ++m)
        acc[m][n] = __builtin_amdgcn_mfma_f32_16x16x32_bf16(af[m], bb, acc[m][n], 0, 0, 0);
    }

    __builtin_amdgcn_sched_barrier(0);
    __builtin_amdgcn_s_barrier();              // buf cur free
    if (i + 2 < nT) STAGE(cur, T(i + 2));
    __builtin_amdgcn_sched_barrier(0);
  }

  // epilogue: D row = l4*4 + r, col = l15 (verified layout)
#pragma unroll
  for (int n = 0; n < 4; ++n) {
    const int col = tileN + wc * 64 + n * 16 + l15;
    const float bv = bias[col];
#pragma unroll
    for (int m = 0; m < 4; ++m) {
      const int rbase = tileM + wr * 64 + m * 16 + l4 * 4;
#pragma unroll
      for (int r = 0; r < 4; ++r)
        out[(size_t)(rbase + r) * N + col] = acc[m][n][r] + bv;
    }
  }
}

// ======================= last-resort fallback (no ws) =======================
#define FBM 128
#define FBN 128
#define FBK 64
__global__ __launch_bounds__(256)
void gptq_gemm_fb(const float* __restrict__ x, const int* __restrict__ qw,
                  const float* __restrict__ scales, const float* __restrict__ bias,
                  float* __restrict__ out, int M, int N, int K, int NG, int GS) {
  __shared__ __bf16 lds_a[FBM * FBK];
  __shared__ __bf16 lds_b[FBN * FBK];
  const int tid = threadIdx.x, lane = tid & 63, wave = tid >> 6;
  const int wr = wave >> 1, wc = wave & 1;
  const int tileM = blockIdx.y * FBM, tileN = blockIdx.x * FBN;
  const int l15 = lane & 15, l4 = lane >> 4;
  f32x4 acc[4][4];
#pragma unroll
  for (int m = 0; m < 4; ++m)
#pragma unroll
    for (int n = 0; n < 4; ++n) acc[m][n] = (f32x4)0.0f;
  for (int k0 = 0; k0 < K; k0 += FBK) {
    const int g = k0 / GS;
#pragma unroll
    for (int i = 0; i < 4; ++i) {
      int u = i * 256 + tid, row = u >> 3, c8 = u & 7;
      const f32x4* src = reinterpret_cast<const f32x4*>(x + (size_t)(tileM + row) * K + k0 + c8 * 8);
      f32x4 v0 = src[0], v1 = src[1];
      bf16x8 w;
      w[0]=(__bf16)v0[0]; w[1]=(__bf16)v0[1]; w[2]=(__bf16)v0[2]; w[3]=(__bf16)v0[3];
      w[4]=(__bf16)v1[0]; w[5]=(__bf16)v1[1]; w[6]=(__bf16)v1[2]; w[7]=(__bf16)v1[3];
      int slot = c8 ^ (row & 7);
      *reinterpret_cast<bf16x8*>(&lds_a[row * FBK + slot * 8]) = w;
    }
#pragma unroll
    for (int i = 0; i < 4; ++i) {
      int u = i * 256 + tid, row = u >> 3, c8 = u & 7;
      int gn = tileN + row;
      const i32x4* src = reinterpret_cast<const i32x4*>(qw + (size_t)gn * K + k0 + c8 * 8);
      i32x4 q0 = src[0], q1 = src[1];
      float s = scales[gn * NG + g];
      bf16x8 w;
      w[0]=(__bf16)((float)q0[0]*s); w[1]=(__bf16)((float)q0[1]*s);
      w[2]=(__bf16)((float)q0[2]*s); w[3]=(__bf16)((float)q0[3]*s);
      w[4]=(__bf16)((float)q1[0]*s); w[5]=(__bf16)((float)q1[1]*s);
      w[6]=(__bf16)((float)q1[2]*s); w[7]=(__bf16)((float)q1[3]*s);
      int slot = c8 ^ (row & 7);
      *reinterpret_cast<bf16x8*>(&lds_b[row * FBK + slot * 8]) = w;
    }
    __syncthreads();
#pragma unroll
    for (int kk = 0; kk < FBK; kk += 32) {
      bf16x8 af[4], bfr[4];
#pragma unroll
      for (int m = 0; m < 4; ++m) {
        int row = wr * 64 + m * 16 + l15, slot = ((kk >> 3) + l4) ^ (row & 7);
        af[m] = *reinterpret_cast<const bf16x8*>(&lds_a[row * FBK + slot * 8]);
      }
#pragma unroll
      for (int n = 0; n < 4; ++n) {
        int row = wc * 64 + n * 16 + l15, slot = ((kk >> 3) + l4) ^ (row & 7);
        bfr[n] = *reinterpret_cast<const bf16x8*>(&lds_b[row * FBK + slot * 8]);
      }
#pragma unroll
      for (int m = 0; m < 4; ++m)
#pragma unroll
        for (int n = 0; n < 4; ++n)
          acc[m][n] = __builtin_amdgcn_mfma_f32_16x16x32_bf16(af[m], bfr[n], acc[m][n], 0, 0, 0);
    }
    __syncthreads();
  }
#pragma unroll
  for (int n = 0; n < 4; ++n) {
    int coln = tileN + wc * 64 + n * 16 + l15;
    float bv = bias[coln];
#pragma unroll
    for (int m = 0; m < 4; ++m) {
      int rbase = tileM + wr * 64 + m * 16 + l4 * 4;
#pragma unroll
      for (int r = 0; r < 4; ++r)
        out[(size_t)(rbase + r) * N + coln] = acc[m][n][r] + bv;
    }
  }
}

extern "C" void kernel_launch(void* const* d_in, const int* in_sizes, int n_in,
                              void* d_out, int out_size, void* d_ws, size_t ws_size,
                              hipStream_t stream) {
  const float* x      = (const float*)d_in[0];
  const int*   qw     = (const int*)d_in[1];
  const float* scales = (const float*)d_in[2];
  const float* bias   = (const float*)d_in[3];
  float*       out    = (float*)d_out;

  const int OUT = in_sizes[3];            // 11008
  const int IN  = in_sizes[1] / OUT;      // 4096
  const int M   = in_sizes[0] / IN;       // 512
  const int NG  = in_sizes[2] / OUT;      // 32
  const int GS  = IN / NG;                // 128

  const size_t needA = (size_t)M * IN * sizeof(__bf16);     // 4.2 MB
  const int nT = IN / GBK;                                  // 128

  const bool ok_fused =
      (ws_size >= needA) && (M % GBM == 0) && (OUT % GBN == 0) &&
      (IN % GBK == 0) && (NG == 32) && (GS == 4 * GBK) && (nT == 4 * NG);

  if (ok_fused) {
    const int gy = M / GBM;               // 4
    const int unitsA = gy * nT * 512;     // 16B units of packed A
    xcvt_p<<<unitsA / 256, 256, 0, stream>>>(x, (__bf16*)d_ws, IN, nT);
    const int gx = OUT / GBN;             // 86
    gptq_fused<<<gx * gy, GTHR, 0, stream>>>(
        (const __bf16*)d_ws, qw, scales, bias, out, OUT, IN, NG, gy);
  } else {
    dim3 grid(OUT / FBN, M / FBM);
    gptq_gemm_fb<<<grid, 256, 0, stream>>>(x, qw, scales, bias, out, M, OUT, IN, NG, GS);
  }
}

// Round 9
// 120.679 us; speedup vs baseline: 1.1811x; 1.1811x over previous
//
#include <hip/hip_runtime.h>
#include <hip/hip_bf16.h>
#include <stdint.h>

using bf16x8 = __attribute__((ext_vector_type(8))) __bf16;
using f32x4  = __attribute__((ext_vector_type(4))) float;
using i32x4  = __attribute__((ext_vector_type(4))) int;

#define GBM 128
#define GBN 128
#define GBK 64
#define GTHR 256   // 4 waves, 2x2; wave tile 64x64, acc 4x4

__device__ __forceinline__ void gload_lds16(const void* g, void* l) {
  __builtin_amdgcn_global_load_lds((const __attribute__((address_space(1))) void*)g,
                                   (__attribute__((address_space(3))) void*)l,
                                   16, 0, 0);
}

// ---- pack B (row-streaming): 8 whole rows per block, sequential reads ----
// Output layout (LDS image): wsB[p][t][unit] with unit = row_in_tile*8 + slot,
// slot = (cu&7) ^ (row&7), cu = global 8-elem k-unit, t = cu>>3.
#define PROWS 8
__global__ __launch_bounds__(256)
void pack_rows(const int* __restrict__ qw, const float* __restrict__ scales,
               __bf16* __restrict__ wsB, int K, int NG, int nT) {
  const int tid = threadIdx.x;
  const int rloc = tid >> 5;                 // 0..7: row within block
  const int ubase = tid & 31;                // unit lane within row
  const int n = blockIdx.x * PROWS + rloc;   // global output row
  const int p = n >> 7;                      // panel (GBN=128)
  const int rit = n & 127;                   // row in tile
  const int rb7 = rit & 7;
  const int nU = K / 8;                      // 512 k-units per row
  const float* srow = scales + (size_t)n * NG;
  const int* qrow = qw + (size_t)n * K;
  __bf16* base = wsB + (size_t)p * nT * (GBN * GBK) + (size_t)rit * 64;

#pragma unroll
  for (int j = 0; j < 16; ++j) {
    const int cu = ubase + j * 32;           // k-unit 0..511 (sequential-ish)
    const i32x4* src = reinterpret_cast<const i32x4*>(qrow + cu * 8);
    i32x4 q0 = src[0], q1 = src[1];
    const float s = srow[cu >> 4];           // GS=128 => 16 units/group
    const int t = cu >> 3;
    const int sl = (cu & 7) ^ rb7;
    bf16x8 w;
    w[0] = (__bf16)((float)q0[0] * s); w[1] = (__bf16)((float)q0[1] * s);
    w[2] = (__bf16)((float)q0[2] * s); w[3] = (__bf16)((float)q0[3] * s);
    w[4] = (__bf16)((float)q1[0] * s); w[5] = (__bf16)((float)q1[1] * s);
    w[6] = (__bf16)((float)q1[2] * s); w[7] = (__bf16)((float)q1[3] * s);
    *reinterpret_cast<bf16x8*>(base + (size_t)t * (GBN * GBK) + sl * 8) = w;
  }
}

// ---- pack A: x fp32 -> bf16, tile-contiguous [by][t][unit], same swizzle ----
__global__ __launch_bounds__(256)
void xcvt_p(const float* __restrict__ x, __bf16* __restrict__ wsA, int K, int nT) {
  const int U  = blockIdx.x * 256 + threadIdx.x;
  const int uu = U & 1023;
  const int tt = (U >> 10) % nT;
  const int by = (U >> 10) / nT;
  const int row = uu >> 3, slot = uu & 7;
  const int c8 = slot ^ (row & 7);
  const f32x4* src = reinterpret_cast<const f32x4*>(
      x + (size_t)(by * GBM + row) * K + tt * GBK + c8 * 8);
  f32x4 a = src[0], b = src[1];
  bf16x8 w;
  w[0] = (__bf16)a[0]; w[1] = (__bf16)a[1]; w[2] = (__bf16)a[2]; w[3] = (__bf16)a[3];
  w[4] = (__bf16)b[0]; w[5] = (__bf16)b[1]; w[6] = (__bf16)b[2]; w[7] = (__bf16)b[3];
  *reinterpret_cast<bf16x8*>(wsA + (size_t)U * 8) = w;
}

// ---- packed-operand GEMM (R7-proven, unchanged) ----
__global__ __launch_bounds__(GTHR, 4)
void gemm_packed(const __bf16* __restrict__ wsA, const __bf16* __restrict__ wsB,
                 const float* __restrict__ bias, float* __restrict__ out,
                 int N, int K, int gy) {
  __shared__ __bf16 As[2][GBM * GBK];   // 2 x 16 KiB
  __shared__ __bf16 Bs[2][GBN * GBK];   // 2 x 16 KiB

  const int tid  = threadIdx.x;
  const int lane = tid & 63;
  const int wv   = tid >> 6;
  const int wr   = wv >> 1;
  const int wc   = wv & 1;

  int wgid = blockIdx.x;
  if ((gridDim.x & 7) == 0) {
    const int q = gridDim.x >> 3;
    wgid = (blockIdx.x & 7) * q + (blockIdx.x >> 3);
  }
  const int bx = wgid / gy;
  const int by = wgid % gy;

  const int l15 = lane & 15;
  const int l4  = lane >> 4;
  const int nT  = K / GBK;

  const __bf16* srcA = wsA + (size_t)by * nT * (GBM * GBK);
  const __bf16* srcB = wsB + (size_t)bx * nT * (GBN * GBK);

  f32x4 acc[4][4];
#pragma unroll
  for (int m = 0; m < 4; ++m)
#pragma unroll
    for (int n = 0; n < 4; ++n) acc[m][n] = (f32x4)0.0f;

  auto STAGE = [&](int buf, int t) {
    const __bf16* a = srcA + (size_t)t * (GBM * GBK);
    const __bf16* b = srcB + (size_t)t * (GBN * GBK);
#pragma unroll
    for (int i = 0; i < 4; ++i) {
      const int ub = (i * 4 + wv) * 64;
      gload_lds16(a + (size_t)(ub + lane) * 8, &As[buf][ub * 8]);
      gload_lds16(b + (size_t)(ub + lane) * 8, &Bs[buf][ub * 8]);
    }
  };

  auto MF = [&](const __bf16* A_, const __bf16* B_) {
#pragma unroll
    for (int kk = 0; kk < 2; ++kk) {
      const int c8 = kk * 4 + l4;
      bf16x8 af[4], bf_[4];
#pragma unroll
      for (int m = 0; m < 4; ++m) {
        const int row = wr * 64 + m * 16 + l15;
        const int slot = c8 ^ (row & 7);
        af[m] = *reinterpret_cast<const bf16x8*>(&A_[row * GBK + slot * 8]);
      }
#pragma unroll
      for (int n = 0; n < 4; ++n) {
        const int col = wc * 64 + n * 16 + l15;
        const int slot = c8 ^ (col & 7);
        bf_[n] = *reinterpret_cast<const bf16x8*>(&B_[col * GBK + slot * 8]);
      }
#pragma unroll
      for (int m = 0; m < 4; ++m)
#pragma unroll
        for (int n = 0; n < 4; ++n)
          acc[m][n] = __builtin_amdgcn_mfma_f32_16x16x32_bf16(af[m], bf_[n], acc[m][n], 0, 0, 0);
    }
  };

  STAGE(0, 0);
  STAGE(1, 1);

  int cur = 0;
  for (int t = 0; t < nT; ++t) {
    if (t + 1 < nT) { asm volatile("s_waitcnt vmcnt(8)" ::: "memory"); }
    else            { asm volatile("s_waitcnt vmcnt(0)" ::: "memory"); }
    __builtin_amdgcn_s_barrier();
    __builtin_amdgcn_sched_barrier(0);
    MF(As[cur], Bs[cur]);
    __builtin_amdgcn_sched_barrier(0);
    __builtin_amdgcn_s_barrier();
    if (t + 2 < nT) STAGE(cur, t + 2);
    __builtin_amdgcn_sched_barrier(0);
    cur ^= 1;
  }

  const int tileM = by * GBM, tileN = bx * GBN;
#pragma unroll
  for (int n = 0; n < 4; ++n) {
    const int col = tileN + wc * 64 + n * 16 + l15;
    const float bv = bias[col];
#pragma unroll
    for (int m = 0; m < 4; ++m) {
      const int rbase = tileM + wr * 64 + m * 16 + l4 * 4;
#pragma unroll
      for (int r = 0; r < 4; ++r)
        out[(size_t)(rbase + r) * N + col] = acc[m][n][r] + bv;
    }
  }
}

// ======================= last-resort fallback (no ws) =======================
#define FBM 128
#define FBN 128
#define FBK 64
__global__ __launch_bounds__(256)
void gptq_gemm_fb(const float* __restrict__ x, const int* __restrict__ qw,
                  const float* __restrict__ scales, const float* __restrict__ bias,
                  float* __restrict__ out, int M, int N, int K, int NG, int GS) {
  __shared__ __bf16 lds_a[FBM * FBK];
  __shared__ __bf16 lds_b[FBN * FBK];
  const int tid = threadIdx.x, lane = tid & 63, wave = tid >> 6;
  const int wr = wave >> 1, wc = wave & 1;
  const int tileM = blockIdx.y * FBM, tileN = blockIdx.x * FBN;
  const int l15 = lane & 15, l4 = lane >> 4;
  f32x4 acc[4][4];
#pragma unroll
  for (int m = 0; m < 4; ++m)
#pragma unroll
    for (int n = 0; n < 4; ++n) acc[m][n] = (f32x4)0.0f;
  for (int k0 = 0; k0 < K; k0 += FBK) {
    const int g = k0 / GS;
#pragma unroll
    for (int i = 0; i < 4; ++i) {
      int u = i * 256 + tid, row = u >> 3, c8 = u & 7;
      const f32x4* src = reinterpret_cast<const f32x4*>(x + (size_t)(tileM + row) * K + k0 + c8 * 8);
      f32x4 v0 = src[0], v1 = src[1];
      bf16x8 w;
      w[0]=(__bf16)v0[0]; w[1]=(__bf16)v0[1]; w[2]=(__bf16)v0[2]; w[3]=(__bf16)v0[3];
      w[4]=(__bf16)v1[0]; w[5]=(__bf16)v1[1]; w[6]=(__bf16)v1[2]; w[7]=(__bf16)v1[3];
      int slot = c8 ^ (row & 7);
      *reinterpret_cast<bf16x8*>(&lds_a[row * FBK + slot * 8]) = w;
    }
#pragma unroll
    for (int i = 0; i < 4; ++i) {
      int u = i * 256 + tid, row = u >> 3, c8 = u & 7;
      int gn = tileN + row;
      const i32x4* src = reinterpret_cast<const i32x4*>(qw + (size_t)gn * K + k0 + c8 * 8);
      i32x4 q0 = src[0], q1 = src[1];
      float s = scales[gn * NG + g];
      bf16x8 w;
      w[0]=(__bf16)((float)q0[0]*s); w[1]=(__bf16)((float)q0[1]*s);
      w[2]=(__bf16)((float)q0[2]*s); w[3]=(__bf16)((float)q0[3]*s);
      w[4]=(__bf16)((float)q1[0]*s); w[5]=(__bf16)((float)q1[1]*s);
      w[6]=(__bf16)((float)q1[2]*s); w[7]=(__bf16)((float)q1[3]*s);
      int slot = c8 ^ (row & 7);
      *reinterpret_cast<bf16x8*>(&lds_b[row * FBK + slot * 8]) = w;
    }
    __syncthreads();
#pragma unroll
    for (int kk = 0; kk < FBK; kk += 32) {
      bf16x8 af[4], bfr[4];
#pragma unroll
      for (int m = 0; m < 4; ++m) {
        int row = wr * 64 + m * 16 + l15, slot = ((kk >> 3) + l4) ^ (row & 7);
        af[m] = *reinterpret_cast<const bf16x8*>(&lds_a[row * FBK + slot * 8]);
      }
#pragma unroll
      for (int n = 0; n < 4; ++n) {
        int row = wc * 64 + n * 16 + l15, slot = ((kk >> 3) + l4) ^ (row & 7);
        bfr[n] = *reinterpret_cast<const bf16x8*>(&lds_b[row * FBK + slot * 8]);
      }
#pragma unroll
      for (int m = 0; m < 4; ++m)
#pragma unroll
        for (int n = 0; n < 4; ++n)
          acc[m][n] = __builtin_amdgcn_mfma_f32_16x16x32_bf16(af[m], bfr[n], acc[m][n], 0, 0, 0);
    }
    __syncthreads();
  }
#pragma unroll
  for (int n = 0; n < 4; ++n) {
    int coln = tileN + wc * 64 + n * 16 + l15;
    float bv = bias[coln];
#pragma unroll
    for (int m = 0; m < 4; ++m) {
      int rbase = tileM + wr * 64 + m * 16 + l4 * 4;
#pragma unroll
      for (int r = 0; r < 4; ++r)
        out[(size_t)(rbase + r) * N + coln] = acc[m][n][r] + bv;
    }
  }
}

extern "C" void kernel_launch(void* const* d_in, const int* in_sizes, int n_in,
                              void* d_out, int out_size, void* d_ws, size_t ws_size,
                              hipStream_t stream) {
  const float* x      = (const float*)d_in[0];
  const int*   qw     = (const int*)d_in[1];
  const float* scales = (const float*)d_in[2];
  const float* bias   = (const float*)d_in[3];
  float*       out    = (float*)d_out;

  const int OUT = in_sizes[3];            // 11008
  const int IN  = in_sizes[1] / OUT;      // 4096
  const int M   = in_sizes[0] / IN;       // 512
  const int NG  = in_sizes[2] / OUT;      // 32
  const int GS  = IN / NG;                // 128

  const size_t needB = (size_t)OUT * IN * sizeof(__bf16);   // 90.2 MB
  const size_t needA = (size_t)M * IN * sizeof(__bf16);     // 4.2 MB
  const int nT = IN / GBK;                                  // 64

  const bool ok_packed =
      (ws_size >= needB + needA) && (M % GBM == 0) && (OUT % GBN == 0) &&
      (IN % (2 * GBK) == 0) && (GS == 128) && (NG == IN / 128) &&
      (OUT % PROWS == 0) && (IN % 8 == 0);

  if (ok_packed) {
    __bf16* wsB = (__bf16*)d_ws;
    __bf16* wsA = (__bf16*)((char*)d_ws + needB);
    pack_rows<<<OUT / PROWS, 256, 0, stream>>>(qw, scales, wsB, IN, NG, nT);
    const int gy = M / GBM;               // 4
    const int unitsA = gy * nT * 1024;
    xcvt_p<<<unitsA / 256, 256, 0, stream>>>(x, wsA, IN, nT);
    const int gx = OUT / GBN;             // 86
    gemm_packed<<<gx * gy, GTHR, 0, stream>>>(wsA, wsB, bias, out, OUT, IN, gy);
  } else {
    dim3 grid(OUT / FBN, M / FBM);
    gptq_gemm_fb<<<grid, 256, 0, stream>>>(x, qw, scales, bias, out, M, OUT, IN, NG, GS);
  }
}